// Round 1
// baseline (408.529 us; speedup 1.0000x reference)
//
#include <hip/hip_runtime.h>
#include <math.h>

typedef unsigned short u16;
typedef __bf16 bf16x8 __attribute__((ext_vector_type(8)));
typedef float f32x4 __attribute__((ext_vector_type(4)));

#define LSEQ 2048
#define NB   4
#define NE   1024
#define NHEAD 8
#define ND1  2048
#define NHD  256
#define NM   8192          // LSEQ*NB
#define CRP  4104          // pitch of shifted-coeff rows (elements, mult of 8)

__device__ __forceinline__ u16 f2bf(float f) {
  unsigned u = __float_as_uint(f);
  u += 0x7FFFu + ((u >> 16) & 1u);       // RTNE
  return (u16)(u >> 16);
}
__device__ __forceinline__ float bf2f(u16 h) {
  return __uint_as_float(((unsigned)h) << 16);
}

// ---------------- f32 -> bf16 bulk convert (n4 = n/4 float4s) ----------------
__global__ __launch_bounds__(256) void cvt_kernel(const float* __restrict__ src,
                                                  u16* __restrict__ dst, int n4) {
  int i = blockIdx.x * 256 + threadIdx.x;
  if (i < n4) {
    float4 v = ((const float4*)src)[i];
    ushort4 o;
    o.x = f2bf(v.x); o.y = f2bf(v.y); o.z = f2bf(v.z); o.w = f2bf(v.w);
    ((ushort4*)dst)[i] = o;
  }
}

// ---------------- build 8 shifted copies of reversed toeplitz coeffs ----------
// cr[h][mm] = c_h[4094-mm] where c_h[t+2047]= (t==0? zero : t>0? pos[t-1] : neg[-t-1])
// cr8[(h*8+s)][m] = cr[h][m+s]  (0 beyond 4094), pitch CRP.
__global__ __launch_bounds__(256) void build_cr8(const float* __restrict__ pos,
                                                 const float* __restrict__ zero,
                                                 const float* __restrict__ neg,
                                                 u16* __restrict__ cr8) {
  int h = blockIdx.x >> 3, s = blockIdx.x & 7;
  u16* out = cr8 + (size_t)blockIdx.x * CRP;
  for (int m = threadIdx.x; m < CRP; m += 256) {
    int mm = m + s;
    float val = 0.f;
    if (mm <= 4094) {
      int t = 2047 - mm;                  // t = i - j
      if (t == 0)      val = zero[h];
      else if (t > 0)  val = pos[h * (LSEQ - 1) + t - 1];
      else             val = neg[h * (LSEQ - 1) + (-t) - 1];
    }
    out[m] = f2bf(val);
  }
}

// ---------------- RMSNorm: x = q / (||q||/sqrt(E) + 1e-8), bf16 out ----------
__global__ __launch_bounds__(256) void rmsnorm_kernel(const float* __restrict__ q,
                                                      u16* __restrict__ x) {
  int row = blockIdx.x;
  float4 v = ((const float4*)(q + (size_t)row * NE))[threadIdx.x];
  float ss = v.x * v.x + v.y * v.y + v.z * v.z + v.w * v.w;
  #pragma unroll
  for (int off = 32; off > 0; off >>= 1) ss += __shfl_down(ss, off, 64);
  __shared__ float wss[4];
  int wave = threadIdx.x >> 6, lane = threadIdx.x & 63;
  if (lane == 0) wss[wave] = ss;
  __syncthreads();
  float tot = wss[0] + wss[1] + wss[2] + wss[3];
  float scale = 1.f / (sqrtf(tot) * 0.03125f + 1e-8f);
  ushort4 o;
  o.x = f2bf(v.x * scale); o.y = f2bf(v.y * scale);
  o.z = f2bf(v.z * scale); o.w = f2bf(v.w * scale);
  ((ushort4*)(x + (size_t)row * NE))[threadIdx.x] = o;
}

// ---------------- transpose v (rows (j,b), cols (h,d)) -> vT[h][b*256+d][j] --
__global__ __launch_bounds__(256) void transpose_v(const u16* __restrict__ v,
                                                   u16* __restrict__ vT) {
  __shared__ u16 s[64 * 66];
  int j0 = blockIdx.x * 64, d0 = blockIdx.y * 64;
  int h = blockIdx.z >> 2, b = blockIdx.z & 3;
  #pragma unroll
  for (int it = 0; it < 16; ++it) {
    int idx = threadIdx.x + 256 * it;
    int r = idx >> 6, c = idx & 63;
    s[r * 66 + c] = v[((size_t)(j0 + r) * NB + b) * ND1 + h * NHD + d0 + c];
  }
  __syncthreads();
  #pragma unroll
  for (int it = 0; it < 16; ++it) {
    int idx = threadIdx.x + 256 * it;
    int r = idx >> 6, c = idx & 63;
    vT[((size_t)h * (NB * NHD) + b * NHD + d0 + r) * LSEQ + j0 + c] = s[c * 66 + r];
  }
}

// ---------------- generic 128x128 MFMA GEMM, C = A(MxK) * W(NxK)^T -----------
// MODE 0: C(bf16) = silu(acc + bias[n])                     (u/v projections)
// MODE 1: A staged from cr8 (toeplitz), epilogue u *= acc   (head GEMM, z=u*y)
// MODE 2: Cf(f32) = acc + bias[n] + resid[m*N+n]            (output GEMM)
#define LDA 72
template <int MODE>
__global__ __launch_bounds__(256) void gemm_kernel(
    const u16* __restrict__ A, const u16* __restrict__ Bw,
    const float* __restrict__ bias, const float* __restrict__ resid,
    u16* __restrict__ Cbf, float* __restrict__ Cf,
    int Msz, int Nsz, int Ksz) {
  __shared__ __align__(16) u16 As[128 * LDA];
  __shared__ __align__(16) u16 Ws[128 * LDA];

  const int tid = threadIdx.x;
  const int lane = tid & 63, wave = tid >> 6;
  const int wr = (wave >> 1) * 64, wc = (wave & 1) * 64;
  const int lr = lane & 15, lq = lane >> 4;
  const int i0 = blockIdx.y * 128, n0 = blockIdx.x * 128;

  const u16* Bh = Bw;
  const u16* Acr = A;
  if (MODE == 1) {
    Bh  = Bw + (size_t)blockIdx.z * Nsz * Ksz;   // vT head base
    Acr = A + (size_t)blockIdx.z * 8 * CRP;      // cr8 head base
  }

  f32x4 acc[4][4];
  #pragma unroll
  for (int a = 0; a < 4; ++a)
    #pragma unroll
    for (int b = 0; b < 4; ++b) acc[a][b] = (f32x4){0.f, 0.f, 0.f, 0.f};

  const int nkt = Ksz >> 6;
  for (int kt = 0; kt < nkt; ++kt) {
    // ---- stage A tile (128 x 64) ----
    #pragma unroll
    for (int it = 0; it < 4; ++it) {
      int vv = tid + 256 * it;
      int r = vv >> 3, c8 = vv & 7;
      uint4 d;
      if (MODE != 1) {
        d = *(const uint4*)(A + (size_t)(i0 + r) * Ksz + kt * 64 + c8 * 8);
      } else {
        int p = 2047 - (i0 + r) + kt * 64;       // cr index of column 0
        int s = p & 7, qq = p - s;               // 8-aligned base in copy s
        d = *(const uint4*)(Acr + (size_t)s * CRP + qq + c8 * 8);
      }
      *(uint4*)&As[r * LDA + c8 * 8] = d;
    }
    // ---- stage W tile (128 x 64) ----
    #pragma unroll
    for (int it = 0; it < 4; ++it) {
      int vv = tid + 256 * it;
      int r = vv >> 3, c8 = vv & 7;
      uint4 d = *(const uint4*)(Bh + (size_t)(n0 + r) * Ksz + kt * 64 + c8 * 8);
      *(uint4*)&Ws[r * LDA + c8 * 8] = d;
    }
    __syncthreads();
    #pragma unroll
    for (int ks = 0; ks < 2; ++ks) {
      bf16x8 af[4], bfr[4];
      #pragma unroll
      for (int rt = 0; rt < 4; ++rt)
        af[rt] = *(const bf16x8*)&As[(wr + rt * 16 + lr) * LDA + ks * 32 + lq * 8];
      #pragma unroll
      for (int ct = 0; ct < 4; ++ct)
        bfr[ct] = *(const bf16x8*)&Ws[(wc + ct * 16 + lr) * LDA + ks * 32 + lq * 8];
      #pragma unroll
      for (int rt = 0; rt < 4; ++rt)
        #pragma unroll
        for (int ct = 0; ct < 4; ++ct)
          acc[rt][ct] = __builtin_amdgcn_mfma_f32_16x16x32_bf16(
              af[rt], bfr[ct], acc[rt][ct], 0, 0, 0);
    }
    __syncthreads();
  }

  // ---- epilogue ----
  #pragma unroll
  for (int rt = 0; rt < 4; ++rt) {
    #pragma unroll
    for (int ct = 0; ct < 4; ++ct) {
      int col = n0 + wc + ct * 16 + lr;
      #pragma unroll
      for (int reg = 0; reg < 4; ++reg) {
        int row = i0 + wr + rt * 16 + lq * 4 + reg;
        float yv = acc[rt][ct][reg];
        if (MODE == 0) {
          float t = yv + bias[col];
          t = t / (1.f + __expf(-t));            // silu
          Cbf[(size_t)row * Nsz + col] = f2bf(t);
        } else if (MODE == 1) {
          int b = col >> 8, d = col & 255;       // col = b*256 + d
          size_t ui = ((size_t)row * NB + b) * ND1 + (size_t)blockIdx.z * NHD + d;
          float uv = bf2f(Cbf[ui]);
          Cbf[ui] = f2bf(uv * yv);               // z = u * y, in place
        } else {
          size_t oi = (size_t)row * Nsz + col;
          Cf[oi] = yv + bias[col] + resid[oi];
        }
      }
    }
  }
}

extern "C" void kernel_launch(void* const* d_in, const int* in_sizes, int n_in,
                              void* d_out, int out_size, void* d_ws, size_t ws_size,
                              hipStream_t stream) {
  const float* q    = (const float*)d_in[0];
  const float* uw   = (const float*)d_in[3];
  const float* ub   = (const float*)d_in[4];
  const float* vw   = (const float*)d_in[5];
  const float* vb   = (const float*)d_in[6];
  const float* ow   = (const float*)d_in[7];
  const float* ob   = (const float*)d_in[8];
  const float* pos  = (const float*)d_in[9];
  const float* zero = (const float*)d_in[10];
  const float* neg  = (const float*)d_in[11];
  float* out = (float*)d_out;

  char* ws = (char*)d_ws;
  u16* x   = (u16*)(ws + 0);            // 8192x1024 bf16 = 16 MiB
  u16* uwb = (u16*)(ws + 16777216);     // 4 MiB
  u16* vwb = (u16*)(ws + 20971520);     // 4 MiB
  u16* owb = (u16*)(ws + 25165824);     // 4 MiB
  u16* u   = (u16*)(ws + 29360128);     // 8192x2048 bf16 = 32 MiB (later z)
  u16* v   = (u16*)(ws + 62914560);     // 32 MiB
  u16* vT  = (u16*)(ws + 96468992);     // 32 MiB
  u16* cr8 = (u16*)(ws + 130023424);    // 8*8*4104*2 = 513 KiB

  cvt_kernel<<<2048, 256, 0, stream>>>(uw, uwb, 524288);
  cvt_kernel<<<2048, 256, 0, stream>>>(vw, vwb, 524288);
  cvt_kernel<<<2048, 256, 0, stream>>>(ow, owb, 524288);
  build_cr8<<<64, 256, 0, stream>>>(pos, zero, neg, cr8);
  rmsnorm_kernel<<<NM, 256, 0, stream>>>(q, x);

  // u = silu(x @ uw^T + ub), v = silu(x @ vw^T + vb)
  gemm_kernel<0><<<dim3(16, 64, 1), 256, 0, stream>>>(x, uwb, ub, nullptr, u, nullptr,
                                                      NM, ND1, NE);
  gemm_kernel<0><<<dim3(16, 64, 1), 256, 0, stream>>>(x, vwb, vb, nullptr, v, nullptr,
                                                      NM, ND1, NE);
  // vT[h][b*256+d][j] = v[(j,b)][h*256+d]
  transpose_v<<<dim3(32, 4, 32), 256, 0, stream>>>(v, vT);
  // per head: y = T_h @ vT_h^T ; z = u*y in place (in u buffer)
  gemm_kernel<1><<<dim3(8, 16, 8), 256, 0, stream>>>(cr8, vT, nullptr, nullptr, u, nullptr,
                                                     LSEQ, NB * NHD, LSEQ);
  // out = z @ ow^T + ob + q
  gemm_kernel<2><<<dim3(8, 64, 1), 256, 0, stream>>>(u, owb, ob, q, nullptr, out,
                                                     NM, NE, ND1);
}